// Round 15
// baseline (182.785 us; speedup 1.0000x reference)
//
#include <hip/hip_runtime.h>
#include <hip/hip_bf16.h>
#include <cstdint>
#include <cstddef>

// ---------------------------------------------------------------------------
// MHA forward, MI355X (gfx950).  Pipeline:
//   K0 : prep = {x fp32->bf16} + {4x weight transpose+cast} fused, 1 launch
//   K1 : QKV GEMM (128x128, m97 structure, XCD-swizzled grid); epilogue
//        scatters Q (pre-scaled log2e/sqrt(d)), K -> [b,h,t,d]; V^T packed
//        bf16x4 stores -> [b,h,d,t]
//   K2 : causal flash attention (swapped QK^T, in-reg softmax, defer-max)
//        R12: 8-wave QBLK=128 blocks (512 thr) -> 2x occupancy, staging/2;
//        per-lane lrun partials (no per-iter reduce); pmax reduce only on
//        rescale.  K/V LDS dbuf+prefetch XOR-swizzled, XCD remap.
//   K3 : out = ctx @ Wo + bo  (64x128 tile, 512 blocks, XCD-swizzled)
// ---------------------------------------------------------------------------

typedef __bf16 bf16_t;
typedef __bf16 bf16x2 __attribute__((ext_vector_type(2)));
typedef __bf16 bf16x4 __attribute__((ext_vector_type(4)));
typedef __bf16 bf16x8 __attribute__((ext_vector_type(8)));
typedef float  f32x4  __attribute__((ext_vector_type(4)));

#define B_SZ 2
#define T_SZ 2048
#define DIN  1024
#define NH   16
#define HD   64

// log2(e)/sqrt(HD): folded into Q at QKV-epilogue time.
#define SCL_Q (0.125f * 1.44269504088896f)

__device__ __forceinline__ void gld_lds16(const void* g, void* l) {
    __builtin_amdgcn_global_load_lds(
        (const __attribute__((address_space(1))) void*)g,
        (__attribute__((address_space(3))) void*)l,
        16, 0, 0);
}

// ---------------------------------------------------------------------------
// K0: fused prep.  Blocks [0,2048): x fp32->bf16 (8 elems/thread).
// Blocks [2048,6144): 32x32 transpose+cast tiles of Wq/Wk/Wv/Wo.
// ---------------------------------------------------------------------------
__global__ __launch_bounds__(256) void prep_kernel(const float* __restrict__ x,
                                                   bf16_t* __restrict__ x_bf,
                                                   const float* __restrict__ Wq,
                                                   const float* __restrict__ Wk,
                                                   const float* __restrict__ Wv,
                                                   const float* __restrict__ Wo,
                                                   bf16_t* __restrict__ Wqkv_t,
                                                   bf16_t* __restrict__ Wo_t) {
    __shared__ float tile[32][33];
    const int bid = blockIdx.x;
    const int tid = threadIdx.x;
    if (bid < 2048) {
        size_t base = ((size_t)bid * 256 + tid) * 8;
        float4 a = *(const float4*)(x + base);
        float4 b = *(const float4*)(x + base + 4);
        bf16x8 v;
        v[0] = (bf16_t)a.x; v[1] = (bf16_t)a.y; v[2] = (bf16_t)a.z; v[3] = (bf16_t)a.w;
        v[4] = (bf16_t)b.x; v[5] = (bf16_t)b.y; v[6] = (bf16_t)b.z; v[7] = (bf16_t)b.w;
        *(bf16x8*)(x_bf + base) = v;
        return;
    }
    const int tb = bid - 2048;          // 0..4095
    const int w  = tb >> 10;            // weight id 0..3
    const int t2 = tb & 1023;
    const int c0 = (t2 & 31) * 32, r0 = (t2 >> 5) * 32;
    const float* src = (w == 0) ? Wq : (w == 1) ? Wk : (w == 2) ? Wv : Wo;
    bf16_t* dst = (w < 3) ? (Wqkv_t + (size_t)w * 1024 * 1024) : Wo_t;
    const int tx = tid & 31, ty = tid >> 5;   // 32 x 8
#pragma unroll
    for (int i = 0; i < 32; i += 8)
        tile[ty + i][tx] = src[(size_t)(r0 + ty + i) * 1024 + c0 + tx];
    __syncthreads();
#pragma unroll
    for (int i = 0; i < 32; i += 8)
        dst[(size_t)(c0 + ty + i) * 1024 + r0 + tx] = (bf16_t)tile[tx][ty + i];
}

// ---------------------------------------------------------------------------
// Shared GEMM tile body (m97 structure, 128x128)
// ---------------------------------------------------------------------------
__device__ __forceinline__ void gemm_tile_body(const bf16_t* __restrict__ A,
                                               const bf16_t* __restrict__ Bt,
                                               int m0, int n0, int K,
                                               f32x4 acc[4][4],
                                               bf16_t* As, bf16_t* Bs) {
    const int tid  = threadIdx.x;
    const int lane = tid & 63;
    const int wave = tid >> 6;
    const int wr   = (wave >> 1) * 64;
    const int wc   = (wave & 1) * 64;

#pragma unroll
    for (int mi = 0; mi < 4; ++mi)
#pragma unroll
        for (int ni = 0; ni < 4; ++ni)
            acc[mi][ni] = (f32x4){0.f, 0.f, 0.f, 0.f};

    for (int k0 = 0; k0 < K; k0 += 32) {
#pragma unroll
        for (int c = 0; c < 2; ++c) {
            int fb = (wave * 2 + c) * 1024;
            int e  = (fb >> 1) + lane * 8;
            int r  = e >> 5;
            int kk = e & 31;
            gld_lds16(A  + (size_t)(m0 + r) * K + k0 + kk, (char*)As + fb);
            gld_lds16(Bt + (size_t)(n0 + r) * K + k0 + kk, (char*)Bs + fb);
        }
        __syncthreads();

        bf16x8 af[4], bfr[4];
#pragma unroll
        for (int mi = 0; mi < 4; ++mi)
            af[mi] = *(const bf16x8*)(As + (wr + mi * 16 + (lane & 15)) * 32 + ((lane >> 4) * 8));
#pragma unroll
        for (int ni = 0; ni < 4; ++ni)
            bfr[ni] = *(const bf16x8*)(Bs + (wc + ni * 16 + (lane & 15)) * 32 + ((lane >> 4) * 8));
#pragma unroll
        for (int mi = 0; mi < 4; ++mi)
#pragma unroll
            for (int ni = 0; ni < 4; ++ni)
                acc[mi][ni] = __builtin_amdgcn_mfma_f32_16x16x32_bf16(af[mi], bfr[ni], acc[mi][ni], 0, 0, 0);
        __syncthreads();
    }
}

// ---------------------------------------------------------------------------
// K1: QKV projection + scatter (Q pre-scaled; V^T packed bf16x4 stores).
// Grid XCD-swizzled: 768 = 8 XCD x 96 contiguous tiles.
// ---------------------------------------------------------------------------
__global__ __launch_bounds__(256, 2) void gemm_qkv_kernel(const bf16_t* __restrict__ A,
                                                          const bf16_t* __restrict__ Bt,
                                                          bf16_t* __restrict__ Qb,
                                                          bf16_t* __restrict__ Kb,
                                                          bf16_t* __restrict__ Vt) {
    __shared__ alignas(16) bf16_t As[128 * 32];
    __shared__ alignas(16) bf16_t Bs[128 * 32];
    const int nTn = 3072 / 128;   // 24
    const int bid = (blockIdx.x & 7) * 96 + (blockIdx.x >> 3);   // XCD swizzle
    int m0 = (bid / nTn) * 128;
    int n0 = (bid % nTn) * 128;
    f32x4 acc[4][4];
    gemm_tile_body(A, Bt, m0, n0, DIN, acc, As, Bs);

    const int lane = threadIdx.x & 63;
    const int wave = threadIdx.x >> 6;
    const int wr = (wave >> 1) * 64, wc = (wave & 1) * 64;
#pragma unroll
    for (int mi = 0; mi < 4; ++mi)
#pragma unroll
        for (int ni = 0; ni < 4; ++ni) {
            int t0 = m0 + wr + mi * 16 + ((lane >> 4) * 4);   // 4-aligned
            int n  = n0 + wc + ni * 16 + (lane & 15);
            int b  = t0 >> 11, tl = t0 & 2047;
            int part = n >> 10, c = n & 1023;
            int h = c >> 6, d = c & 63;
            if (part == 2) {
                bf16x4 pv;
#pragma unroll
                for (int j = 0; j < 4; ++j) pv[j] = (bf16_t)acc[mi][ni][j];
                *(bf16x4*)&Vt[((size_t)(b * NH + h) * HD + d) * T_SZ + tl] = pv;
            } else if (part == 0) {
#pragma unroll
                for (int j = 0; j < 4; ++j)
                    Qb[(((size_t)(b * NH + h) * T_SZ + tl + j) << 6) + d] =
                        (bf16_t)(acc[mi][ni][j] * SCL_Q);
            } else {
#pragma unroll
                for (int j = 0; j < 4; ++j)
                    Kb[(((size_t)(b * NH + h) * T_SZ + tl + j) << 6) + d] =
                        (bf16_t)acc[mi][ni][j];
            }
        }
}

// ---------------------------------------------------------------------------
// K2: causal flash attention.  8 waves x 16 q-rows = 128-row Q block; K/V
// tiles (64x64) LDS-staged, dbuf+prefetch, XOR swizzle, shared by 8 waves.
// Swapped QK^T: lane (rgrp,rcol) owns q-row (q0+rcol), scores
// k = k0+ni*16+rgrp*4+j in s_acc[ni][j].  Per-lane lrun partials; pmax
// reduce only inside the rare rescale branch (defer-max THR=8).
// Waves 0-3 run one fully-masked tail iteration (all-zero P, benign).
// ---------------------------------------------------------------------------
__global__ __launch_bounds__(512, 4) void attn_kernel(const bf16_t* __restrict__ Qb,
                                                      const bf16_t* __restrict__ Kb,
                                                      const bf16_t* __restrict__ Vt,
                                                      bf16_t* __restrict__ ctx) {
    __shared__ alignas(16) bf16_t Ks[2][64 * 64];     // 16KB
    __shared__ alignas(16) bf16_t Vs[2][64 * 64];     // 16KB (rows are d)
    __shared__ alignas(16) bf16_t P_lds[8][16][72];   // 18KB, +8 pad

    const int raw = blockIdx.x;         // 0..511
    const int xcd = raw & 7;
    const int jj  = raw >> 3;           // 0..63
    const int bh  = xcd * 4 + (jj & 3); // 4 heads per XCD -> 2MB K/V in L2
    const int qt  = 15 - (jj >> 2);     // big q-tiles dispatch first

    const int lane = threadIdx.x & 63;
    const int wave = threadIdx.x >> 6;  // 0..7

    const bf16_t* Qp = Qb + (size_t)bh * T_SZ * HD;
    const bf16_t* Kp = Kb + (size_t)bh * T_SZ * HD;
    const bf16_t* Vp = Vt + (size_t)bh * HD * T_SZ;

    const int q0 = qt * 128 + wave * 16;
    const int rgrp = lane >> 4;              // 0..3
    const int rcol = lane & 15;              // 0..15

    const int st_r  = (lane >> 3);           // 0..7
    const int st_sl = lane & 7;

    // Q fragments (row=lane&15, k=rgrp*8+i per 32-chunk)
    bf16x8 qa[2];
#pragma unroll
    for (int s = 0; s < 2; ++s)
        qa[s] = *(const bf16x8*)(Qp + (size_t)(q0 + rcol) * HD + s * 32 + rgrp * 8);

    f32x4 o[4];                              // o[di][j] = O[q0+rgrp*4+j][di*16+rcol]
#pragma unroll
    for (int di = 0; di < 4; ++di) o[di] = (f32x4){0.f, 0.f, 0.f, 0.f};
    float mrun = -__builtin_inff();          // row max (uniform over rgrp)
    float lrun = 0.f;                        // PER-LANE partial sum

    const int nkt = 2 * qt + 2;              // k-tiles to process

    // stage: wave w covers rows w*8..w*8+7 of the 64x64 tile (1KB per wave).
#define STAGE(BUF, KT)                                                          \
    {                                                                           \
        const int k0s = (KT) * 64;                                              \
        int r  = wave * 8 + st_r;                                               \
        int sl = st_sl ^ (r & 7);                                               \
        gld_lds16(Kp + (size_t)(k0s + r) * HD + sl * 8,                         \
                  (char*)&Ks[BUF][0] + wave * 1024);                            \
        gld_lds16(Vp + (size_t)r * T_SZ + k0s + sl * 8,                         \
                  (char*)&Vs[BUF][0] + wave * 1024);                            \
    }

    STAGE(0, 0);
    __syncthreads();
    int buf = 0;

    for (int kt = 0; kt < nkt; ++kt) {
        if (kt + 1 < nkt) STAGE(buf ^ 1, kt + 1);

        const char* Kb_l = (const char*)&Ks[buf][0];
        const char* Vb_l = (const char*)&Vs[buf][0];
        const int k0 = kt * 64;

        // ---- S^T = K Q^T  (swapped operands) ----
        f32x4 s_acc[4];
#pragma unroll
        for (int ni = 0; ni < 4; ++ni) s_acc[ni] = (f32x4){0.f, 0.f, 0.f, 0.f};
#pragma unroll
        for (int s = 0; s < 2; ++s)
#pragma unroll
            for (int ni = 0; ni < 4; ++ni) {
                int fr = ni * 16 + rcol;
                bf16x8 kb = *(const bf16x8*)(Kb_l + fr * 128 + (((s * 4 + rgrp) ^ (fr & 7)) << 4));
                s_acc[ni] = __builtin_amdgcn_mfma_f32_16x16x32_bf16(kb, qa[s], s_acc[ni], 0, 0, 0);
            }

        // ---- V fragments early (independent of softmax) ----
        bf16x8 vf[2][4];
#pragma unroll
        for (int s = 0; s < 2; ++s)
#pragma unroll
            for (int di = 0; di < 4; ++di) {
                int fv = di * 16 + rcol;
                vf[s][di] = *(const bf16x8*)(Vb_l + fv * 128 + (((s * 4 + rgrp) ^ (fv & 7)) << 4));
            }

        // ---- mask (diagonal/tail tiles) + per-lane max ----
        float ptile[4][4];
        float pmax = -__builtin_inff();
        if (k0 + 63 > q0) {                  // some lane may need masking
            const int qabs = q0 + rcol;
#pragma unroll
            for (int ni = 0; ni < 4; ++ni)
#pragma unroll
                for (int j = 0; j < 4; ++j) {
                    int kidx = k0 + ni * 16 + rgrp * 4 + j;
                    float v = s_acc[ni][j];
                    if (kidx > qabs) v = -__builtin_inff();
                    ptile[ni][j] = v;
                    pmax = fmaxf(pmax, v);
                }
        } else {
#pragma unroll
            for (int ni = 0; ni < 4; ++ni)
#pragma unroll
                for (int j = 0; j < 4; ++j) {
                    float v = s_acc[ni][j];
                    ptile[ni][j] = v;
                    pmax = fmaxf(pmax, v);
                }
        }

        // ---- defer-max (THR=8): per-lane check; reduce only on rescale ----
        const bool fullb = __any(pmax > mrun + 8.f);
        if (fullb) {
            pmax = fmaxf(pmax, __shfl_xor(pmax, 16));   // row max over rgrp
            pmax = fmaxf(pmax, __shfl_xor(pmax, 32));
            float newm = fmaxf(mrun, pmax);
            float a_self = exp2f(mrun - newm);          // exp2(-inf)=0 first tile
            mrun = newm;
            lrun *= a_self;                             // per-lane partial scales
#pragma unroll
            for (int j = 0; j < 4; ++j) {
                float aj = __shfl(a_self, (lane & 48) | (rgrp * 4 + j));
#pragma unroll
                for (int di = 0; di < 4; ++di) o[di][j] *= aj;
            }
        }
        float rsum = 0.f;
#pragma unroll
        for (int ni = 0; ni < 4; ++ni)
#pragma unroll
            for (int j = 0; j < 4; ++j) {
                float p = exp2f(ptile[ni][j] - mrun);   // masked -> 0
                ptile[ni][j] = p;
                rsum += p;
            }
        lrun += rsum;                                   // no per-iter reduce

        // ---- P -> LDS row-major [q=rcol][k], packed b32 writes ----
#pragma unroll
        for (int ni = 0; ni < 4; ++ni)
#pragma unroll
            for (int jp = 0; jp < 2; ++jp) {
                bf16x2 pk;
                pk[0] = (bf16_t)ptile[ni][2 * jp];
                pk[1] = (bf16_t)ptile[ni][2 * jp + 1];
                *(bf16x2*)&P_lds[wave][rcol][ni * 16 + rgrp * 4 + 2 * jp] = pk;
            }
        // ---- O += P V ----
#pragma unroll
        for (int s = 0; s < 2; ++s) {
            bf16x8 pa = *(const bf16x8*)(&P_lds[wave][rcol][s * 32 + rgrp * 8]);
#pragma unroll
            for (int di = 0; di < 4; ++di)
                o[di] = __builtin_amdgcn_mfma_f32_16x16x32_bf16(pa, vf[s][di], o[di], 0, 0, 0);
        }
        __syncthreads();   // prefetch landed (vmcnt) + all waves done with buf
        buf ^= 1;
    }
#undef STAGE

    // ---- epilogue: reduce lrun over rgrp, then ctx = o / l ----
    lrun += __shfl_xor(lrun, 16);
    lrun += __shfl_xor(lrun, 32);
    const int b = bh >> 4, h = bh & 15;
    float invl[4];
#pragma unroll
    for (int j = 0; j < 4; ++j) {
        float lj = __shfl(lrun, (lane & 48) | (rgrp * 4 + j));
        invl[j] = 1.f / lj;
    }
#pragma unroll
    for (int di = 0; di < 4; ++di)
#pragma unroll
        for (int j = 0; j < 4; ++j) {
            int q = q0 + rgrp * 4 + j;
            int d = di * 16 + rcol;
            ctx[((size_t)(b * T_SZ + q) * NH + h) * HD + d] = (bf16_t)(o[di][j] * invl[j]);
        }
}

// ---------------------------------------------------------------------------
// K3: out = ctx @ Wo + bo.  64x128 tile, 4 waves 2x2 (32x64 each), 512
// blocks = 2/CU, XCD-swizzled grid.
// ---------------------------------------------------------------------------
__global__ __launch_bounds__(256, 3) void gemm_out_kernel(const bf16_t* __restrict__ A,
                                                          const bf16_t* __restrict__ Bt,
                                                          const float* __restrict__ bias,
                                                          float* __restrict__ out) {
    __shared__ alignas(16) bf16_t As[64 * 32];    // 4KB
    __shared__ alignas(16) bf16_t Bs[128 * 32];   // 8KB
    const int nTn = 1024 / 128;   // 8
    const int bid = (blockIdx.x & 7) * 64 + (blockIdx.x >> 3);   // XCD swizzle
    int m0 = (bid / nTn) * 64;
    int n0 = (bid % nTn) * 128;

    const int tid  = threadIdx.x;
    const int lane = tid & 63;
    const int wave = tid >> 6;
    const int wr   = (wave >> 1) * 32;   // 0 / 32
    const int wc   = (wave & 1) * 64;    // 0 / 64

    f32x4 acc[2][4];
#pragma unroll
    for (int mi = 0; mi < 2; ++mi)
#pragma unroll
        for (int ni = 0; ni < 4; ++ni)
            acc[mi][ni] = (f32x4){0.f, 0.f, 0.f, 0.f};

    for (int k0 = 0; k0 < DIN; k0 += 32) {
        {
            int fb = wave * 1024;
            int e  = (fb >> 1) + lane * 8;
            int r  = e >> 5;
            int kk = e & 31;
            gld_lds16(A + (size_t)(m0 + r) * DIN + k0 + kk, (char*)As + fb);
        }
#pragma unroll
        for (int c = 0; c < 2; ++c) {
            int fb = (wave * 2 + c) * 1024;
            int e  = (fb >> 1) + lane * 8;
            int r  = e >> 5;
            int kk = e & 31;
            gld_lds16(Bt + (size_t)(n0 + r) * DIN + k0 + kk, (char*)Bs + fb);
        }
        __syncthreads();

        bf16x8 af[2], bfr[4];
#pragma unroll
        for (int mi = 0; mi < 2; ++mi)
            af[mi] = *(const bf16x8*)(As + (wr + mi * 16 + (lane & 15)) * 32 + ((lane >> 4) * 8));
#pragma unroll
        for (int ni = 0; ni < 4; ++ni)
            bfr[ni] = *(const bf16x8*)(Bs + (wc + ni * 16 + (lane & 15)) * 32 + ((lane >> 4) * 8));
#pragma unroll
        for (int mi = 0; mi < 2; ++mi)
#pragma unroll
            for (int ni = 0; ni < 4; ++ni)
                acc[mi][ni] = __builtin_amdgcn_mfma_f32_16x16x32_bf16(af[mi], bfr[ni], acc[mi][ni], 0, 0, 0);
        __syncthreads();
    }

#pragma unroll
    for (int mi = 0; mi < 2; ++mi)
#pragma unroll
        for (int ni = 0; ni < 4; ++ni) {
            int n = n0 + wc + ni * 16 + (lane & 15);
            float bv = bias[n];
#pragma unroll
            for (int j = 0; j < 4; ++j) {
                int m = m0 + wr + mi * 16 + ((lane >> 4) * 4) + j;
                out[(size_t)m * 1024 + n] = acc[mi][ni][j] + bv;
            }
        }
}

// ---------------------------------------------------------------------------
// Launch.  Workspace layout (48 MB total).
// ---------------------------------------------------------------------------
extern "C" void kernel_launch(void* const* d_in, const int* in_sizes, int n_in,
                              void* d_out, int out_size, void* d_ws, size_t ws_size,
                              hipStream_t stream) {
    const float* x  = (const float*)d_in[0];
    const float* Wq = (const float*)d_in[1];
    const float* Wk = (const float*)d_in[2];
    const float* Wv = (const float*)d_in[3];
    const float* Wo = (const float*)d_in[4];
    const float* bo = (const float*)d_in[5];
    float* out = (float*)d_out;

    char* ws = (char*)d_ws;
    bf16_t* x_bf   = (bf16_t*)(ws);
    bf16_t* Wqkv_t = (bf16_t*)(ws + ((size_t)8 << 20));
    bf16_t* Wo_t   = (bf16_t*)(ws + ((size_t)14 << 20));
    bf16_t* Qb     = (bf16_t*)(ws + ((size_t)16 << 20));
    bf16_t* Kb     = (bf16_t*)(ws + ((size_t)24 << 20));
    bf16_t* Vt     = (bf16_t*)(ws + ((size_t)32 << 20));
    bf16_t* ctx    = (bf16_t*)(ws + ((size_t)40 << 20));

    // K0: fused cast + 4 weight transposes (1 launch, 6144 blocks)
    prep_kernel<<<6144, 256, 0, stream>>>(x, x_bf, Wq, Wk, Wv, Wo, Wqkv_t, Wo_t);
    // K1: QKV projection (M=4096, N=3072, K=1024), XCD-swizzled
    gemm_qkv_kernel<<<32 * 24, 256, 0, stream>>>(x_bf, Wqkv_t, Qb, Kb, Vt);
    // K2: causal attention, 8-wave QBLK=128 blocks (XCD remap inside)
    attn_kernel<<<B_SZ * NH * 16, 512, 0, stream>>>(Qb, Kb, Vt, ctx);
    // K3: output projection (M=4096, N=1024, K=1024), 64x128 tiles
    gemm_out_kernel<<<64 * 8, 256, 0, stream>>>(ctx, Wo_t, bo, out);
}